// Round 1
// baseline (1073.395 us; speedup 1.0000x reference)
//
#include <hip/hip_runtime.h>
#include <cstdint>
#include <cstddef>

#define BATCH 8
#define SEQ   4096
#define DS    512
#define JPL   8   // states per lane (64 lanes * 8 = 512)

// ---- DPP wave64 reduction (gfx9-style): row_shr 1/2/4/8, row_bcast15/31 ----
template <int CTRL>
__device__ __forceinline__ float dpp_add(float v) {
  int t = __builtin_amdgcn_update_dpp(0, __builtin_bit_cast(int, v), CTRL, 0xF, 0xF, true);
  return v + __builtin_bit_cast(float, t);
}

__device__ __forceinline__ float wave_sum64(float v) {
  v = dpp_add<0x111>(v);  // row_shr:1
  v = dpp_add<0x112>(v);  // row_shr:2
  v = dpp_add<0x114>(v);  // row_shr:4
  v = dpp_add<0x118>(v);  // row_shr:8  -> lane15/31/47/63 hold row sums
  v = dpp_add<0x142>(v);  // row_bcast15 -> lane31 = sum(0..31), lane63 = sum(32..63)
  v = dpp_add<0x143>(v);  // row_bcast31 -> lane63 = sum(0..63)
  return v;               // valid in lane 63
}

__device__ __forceinline__ float bcast63(float v) {
  return __builtin_bit_cast(float,
      __builtin_amdgcn_readlane(__builtin_bit_cast(int, v), 63));
}

// ---------------- scan kernel: one wave per batch element -------------------
__global__ __launch_bounds__(64, 1) void ssm_scan(
    const float* __restrict__ x, const float* __restrict__ vol,
    const float* __restrict__ llr, const float* __restrict__ logb,
    const float* __restrict__ cvec, const float* __restrict__ lstp,
    const float* __restrict__ vgat, const float* __restrict__ lnw,
    const float* __restrict__ lnb, float* __restrict__ s_out)
{
  const int b    = blockIdx.x;
  const int lane = threadIdx.x;
  const int n0   = lane * JPL;

  // per-lane constants (one-time setup)
  float a[JPL], bd[JPL], w[JPL], bias[JPL], cc[JPL], gate[JPL];
#pragma unroll
  for (int j = 0; j < JPL; ++j) {
    int n = n0 + j;
    float lam = -expf(llr[n]);
    float st  = expf(lstp[n]);
    float z   = st * lam;
    float ad  = (2.0f + z) / (2.0f - z);
    a[j]    = ad;
    bd[j]   = st * (1.0f + ad) * expf(logb[n]) * 0.5f;
    w[j]    = lnw[n];
    bias[j] = lnb[n];
    cc[j]   = cvec[n];
    gate[j] = 1.0f / (1.0f + expf(-vgat[n]));
  }

  const float* xp = x + (size_t)b * SEQ * DS + n0;
  const float* vp = vol + (size_t)b * SEQ;
  float* sp = s_out + (size_t)b * SEQ;

  float h[JPL];
#pragma unroll
  for (int j = 0; j < JPL; ++j) h[j] = 0.0f;

  float4 XA[16], XB[16], VA[2], VB[2];

  auto load_blk = [&](float4 (&X)[16], float4 (&V)[2], int T) {
    const float* xb = xp + (size_t)T * DS;
#pragma unroll
    for (int u = 0; u < 8; ++u) {
      X[2 * u]     = *(const float4*)(xb + u * DS);
      X[2 * u + 1] = *(const float4*)(xb + u * DS + 4);
    }
    V[0] = *(const float4*)(vp + T);
    V[1] = *(const float4*)(vp + T + 4);
  };

  auto proc_blk = [&](const float4 (&X)[16], const float4 (&V)[2], int T) {
    float sacc[8];
#pragma unroll
    for (int u = 0; u < 8; ++u) {
      float4 vv = V[u >> 2];
      float vt = ((u & 3) == 0) ? vv.x : ((u & 3) == 1) ? vv.y
                 : ((u & 3) == 2) ? vv.z : vv.w;
      float4 xa = X[2 * u], xb2 = X[2 * u + 1];
      float xr[JPL] = {xa.x, xa.y, xa.z, xa.w, xb2.x, xb2.y, xb2.z, xb2.w};

      // diagonal SSM update
      float hr[JPL];
#pragma unroll
      for (int j = 0; j < JPL; ++j) hr[j] = fmaf(a[j], h[j], bd[j] * xr[j]);

      // sum & sumsq trees (per-lane partials over 8 states)
      float s1 = ((hr[0] + hr[1]) + (hr[2] + hr[3])) +
                 ((hr[4] + hr[5]) + (hr[6] + hr[7]));
      float q[JPL];
#pragma unroll
      for (int j = 0; j < JPL; ++j) q[j] = hr[j] * hr[j];
      float s2 = ((q[0] + q[1]) + (q[2] + q[3])) +
                 ((q[4] + q[5]) + (q[6] + q[7]));

      s1 = wave_sum64(s1);
      s2 = wave_sum64(s2);
      float mu  = bcast63(s1) * (1.0f / DS);
      float m2  = bcast63(s2) * (1.0f / DS);
      float var = fmaf(-mu, mu, m2);
      float inv = __builtin_amdgcn_rsqf(var + 1e-5f);

      // layernorm + volatility gate; carry h = post-gate state
#pragma unroll
      for (int j = 0; j < JPL; ++j) {
        float hln = fmaf(hr[j] - mu, inv * w[j], bias[j]);
        float rg  = __builtin_amdgcn_rcpf(fmaf(gate[j], vt, 1.0f));
        h[j] = hln * rg;
      }

      // readout scalar s_t = sum(h * c)
      float pc[JPL];
#pragma unroll
      for (int j = 0; j < JPL; ++j) pc[j] = h[j] * cc[j];
      float sd = ((pc[0] + pc[1]) + (pc[2] + pc[3])) +
                 ((pc[4] + pc[5]) + (pc[6] + pc[7]));
      sacc[u] = wave_sum64(sd);  // valid in lane 63
    }
    if (lane == 63) {
#pragma unroll
      for (int u = 0; u < 8; ++u) sp[T + u] = sacc[u];
    }
  };

  // software-pipelined: process block k while block k+1 is in flight
  load_blk(XA, VA, 0);
  int T = 0;
  for (int it = 0; it < (SEQ / 16) - 1; ++it, T += 16) {
    load_blk(XB, VB, T + 8);
    proc_blk(XA, VA, T);
    load_blk(XA, VA, T + 16);
    proc_blk(XB, VB, T + 8);
  }
  load_blk(XB, VB, T + 8);
  proc_blk(XA, VA, T);
  proc_blk(XB, VB, T + 8);
}

// ------------- epilogue: out = coef*x + c1*s[b,t], memory-bound -------------
__global__ __launch_bounds__(256) void ssm_out_kernel(
    const float* __restrict__ x, const float* __restrict__ s,
    const float* __restrict__ alpha_p, const float* __restrict__ logd_p,
    float* __restrict__ out)
{
  float al   = 1.0f / (1.0f + expf(-alpha_p[0]));
  float dd   = expf(logd_p[0]);
  float coef = fmaf(1.0f - al, dd, al);
  float c1   = 1.0f - al;

  const size_t total4 = (size_t)BATCH * SEQ * DS / 4;
  size_t i = (size_t)blockIdx.x * blockDim.x + threadIdx.x;
  const size_t stride = (size_t)gridDim.x * blockDim.x;
  const float4* x4 = (const float4*)x;
  float4* o4 = (float4*)out;
  for (; i < total4; i += stride) {
    float4 xv = x4[i];
    float sv  = s[i >> 7];  // 128 float4 per (b,t)
    float4 o;
    o.x = fmaf(coef, xv.x, c1 * sv);
    o.y = fmaf(coef, xv.y, c1 * sv);
    o.z = fmaf(coef, xv.z, c1 * sv);
    o.w = fmaf(coef, xv.w, c1 * sv);
    o4[i] = o;
  }
}

extern "C" void kernel_launch(void* const* d_in, const int* in_sizes, int n_in,
                              void* d_out, int out_size, void* d_ws, size_t ws_size,
                              hipStream_t stream) {
  const float* x    = (const float*)d_in[0];   // [8,4096,512]
  const float* vol  = (const float*)d_in[1];   // [8,4096,1]
  const float* llr  = (const float*)d_in[2];   // [512]
  const float* logb = (const float*)d_in[3];   // [512,1]
  const float* cvec = (const float*)d_in[4];   // [1,512]
  const float* logd = (const float*)d_in[5];   // [1]
  const float* lstp = (const float*)d_in[6];   // [512]
  const float* vgat = (const float*)d_in[7];   // [512]
  const float* alph = (const float*)d_in[8];   // [1]
  const float* lnw  = (const float*)d_in[9];   // [512]
  const float* lnb  = (const float*)d_in[10];  // [512]

  float* s_ws = (float*)d_ws;  // needs BATCH*SEQ*4 = 128 KB

  ssm_scan<<<BATCH, 64, 0, stream>>>(x, vol, llr, logb, cvec, lstp, vgat,
                                     lnw, lnb, s_ws);
  ssm_out_kernel<<<4096, 256, 0, stream>>>(x, s_ws, alph, logd, (float*)d_out);
}

// Round 2
// 773.045 us; speedup vs baseline: 1.3885x; 1.3885x over previous
//
#include <hip/hip_runtime.h>
#include <cstdint>
#include <cstddef>

#define BATCH 8
#define SEQ   4096
#define DS    512
#define JPL   8          // states per lane (64 lanes * 8 = 512)
#define BLK   4          // time steps per prefetch block
#define NB    (SEQ / BLK)

typedef float v2f __attribute__((ext_vector_type(2)));
typedef float v4f __attribute__((ext_vector_type(4)));

static __device__ __forceinline__ v2f lo2(v4f x) { return __builtin_shufflevector(x, x, 0, 1); }
static __device__ __forceinline__ v2f hi2(v4f x) { return __builtin_shufflevector(x, x, 2, 3); }

// ---- DPP wave64 reduction: row_shr 1/2/4/8, row_bcast15/31 -> lane 63 ----
template <int CTRL>
__device__ __forceinline__ float dpp_add(float v) {
  int t = __builtin_amdgcn_update_dpp(0, __builtin_bit_cast(int, v), CTRL, 0xF, 0xF, true);
  return v + __builtin_bit_cast(float, t);
}
__device__ __forceinline__ float wave_sum64(float v) {
  v = dpp_add<0x111>(v);
  v = dpp_add<0x112>(v);
  v = dpp_add<0x114>(v);
  v = dpp_add<0x118>(v);
  v = dpp_add<0x142>(v);
  v = dpp_add<0x143>(v);
  return v;  // valid in lane 63
}
__device__ __forceinline__ float bcast63(float v) {
  return __builtin_bit_cast(float, __builtin_amdgcn_readlane(__builtin_bit_cast(int, v), 63));
}

// ---- rg[b,t,n] = 1 / (1 + sigmoid(vgat[n]) * vol[b,t]) : bulk, memory-bound ----
__global__ __launch_bounds__(256) void rg_kernel(const float* __restrict__ vol,
                                                 const float* __restrict__ vgat,
                                                 float* __restrict__ rg) {
  int idx = blockIdx.x * 256 + threadIdx.x;     // float4 index; total BATCH*SEQ*128
  int nt  = idx & 127;
  int bt  = idx >> 7;
  float v = vol[bt];
  v4f g = *(const v4f*)(vgat + nt * 4);
  v4f r;
#pragma unroll
  for (int k = 0; k < 4; ++k) {
    float gg = 1.0f / (1.0f + expf(-g[k]));
    r[k] = 1.0f / (1.0f + gg * v);
  }
  *(v4f*)(rg + (size_t)idx * 4) = r;
}

// ---------------- scan kernel: one wave per batch element -------------------
// RGP: gate reciprocal streamed from global (precomputed) vs inline v_rcp.
// PART: store 64 per-lane readout partials per step (epilogue reduces) vs
//       in-scan DPP reduce + scalar store.
template <bool RGP, bool PART>
__global__ __launch_bounds__(64, 1) void ssm_scan(
    const float* __restrict__ x, const float* __restrict__ vol,
    const float* __restrict__ llr, const float* __restrict__ logb,
    const float* __restrict__ cvec, const float* __restrict__ lstp,
    const float* __restrict__ vgat, const float* __restrict__ lnw,
    const float* __restrict__ lnb, const float* __restrict__ rg_g,
    float* __restrict__ outp)
{
  const int b    = blockIdx.x;
  const int lane = threadIdx.x;
  const int n0   = lane * JPL;

  v2f a[4], bd[4], w[4], bias[4], cc[4], gate[4];
#pragma unroll
  for (int j = 0; j < JPL; ++j) {
    int n = n0 + j;
    float lam = -expf(llr[n]);
    float st  = expf(lstp[n]);
    float z   = st * lam;
    float ad  = (2.0f + z) / (2.0f - z);
    a[j >> 1][j & 1]    = ad;
    bd[j >> 1][j & 1]   = st * (1.0f + ad) * expf(logb[n]) * 0.5f;
    w[j >> 1][j & 1]    = lnw[n];
    bias[j >> 1][j & 1] = lnb[n];
    cc[j >> 1][j & 1]   = cvec[n];
    gate[j >> 1][j & 1] = RGP ? 0.0f : (1.0f / (1.0f + expf(-vgat[n])));
  }

  const float* xp = x + (size_t)b * SEQ * DS + n0;
  const float* vp = vol + (size_t)b * SEQ;
  const float* rp = RGP ? (rg_g + (size_t)b * SEQ * DS + n0) : nullptr;
  float* pp = outp + (size_t)b * SEQ * (PART ? 64 : 1);

  v2f h[4];
#pragma unroll
  for (int k = 0; k < 4; ++k) h[k] = (v2f){0.0f, 0.0f};

  v4f XA[2 * BLK], XB[2 * BLK], RA[2 * BLK], RB[2 * BLK];
  v4f VA = {0, 0, 0, 0}, VB = {0, 0, 0, 0};

  auto load_blk = [&](v4f (&X)[2 * BLK], v4f (&R)[2 * BLK], v4f& V, int T) {
    const float* xb = xp + (size_t)T * DS;
#pragma unroll
    for (int u = 0; u < BLK; ++u) {
      X[2 * u]     = *(const v4f*)(xb + u * DS);
      X[2 * u + 1] = *(const v4f*)(xb + u * DS + 4);
    }
    if constexpr (RGP) {
      const float* rb = rp + (size_t)T * DS;
#pragma unroll
      for (int u = 0; u < BLK; ++u) {
        R[2 * u]     = *(const v4f*)(rb + u * DS);
        R[2 * u + 1] = *(const v4f*)(rb + u * DS + 4);
      }
    } else {
      V = *(const v4f*)(vp + T);
    }
  };

  auto proc_blk = [&](const v4f (&X)[2 * BLK], const v4f (&R)[2 * BLK], v4f V, int T) {
    float sacc[BLK];
#pragma unroll
    for (int u = 0; u < BLK; ++u) {
      v2f xs[4] = {lo2(X[2 * u]), hi2(X[2 * u]), lo2(X[2 * u + 1]), hi2(X[2 * u + 1])};

      // diagonal SSM update: hr = a*h + bd*x   (pairs -> v_pk_fma_f32)
      v2f hr[4];
#pragma unroll
      for (int k = 0; k < 4; ++k)
        hr[k] = __builtin_elementwise_fma(a[k], h[k], bd[k] * xs[k]);

      // per-lane partial sum & sumsq
      v2f t01 = hr[0] + hr[1], t23 = hr[2] + hr[3];
      v2f ts = t01 + t23;
      float s1 = ts.x + ts.y;
      v2f q01 = hr[0] * hr[0] + hr[1] * hr[1];
      v2f q23 = hr[2] * hr[2] + hr[3] * hr[3];
      v2f qs = q01 + q23;
      float s2 = qs.x + qs.y;

      s1 = bcast63(wave_sum64(s1));
      s2 = bcast63(wave_sum64(s2));
      float mu  = s1 * (1.0f / DS);
      float m2  = s2 * (1.0f / DS);
      float var = __builtin_fmaf(-mu, mu, m2);
      float inv = __builtin_amdgcn_rsqf(var + 1e-5f);

      // gate reciprocal: streamed (RGP) or inline v_rcp
      v2f rs[4];
      if constexpr (RGP) {
        rs[0] = lo2(R[2 * u]); rs[1] = hi2(R[2 * u]);
        rs[2] = lo2(R[2 * u + 1]); rs[3] = hi2(R[2 * u + 1]);
      } else {
        float vt = V[u];
#pragma unroll
        for (int k = 0; k < 4; ++k) {
          v2f den = gate[k] * vt + 1.0f;
          rs[k][0] = __builtin_amdgcn_rcpf(den[0]);
          rs[k][1] = __builtin_amdgcn_rcpf(den[1]);
        }
      }

      // layernorm (restructured: hln = hr*niw + (bias - mu*niw)) + gating
#pragma unroll
      for (int k = 0; k < 4; ++k) {
        v2f niw = w[k] * inv;
        v2f hb  = bias[k] - niw * mu;
        v2f hln = __builtin_elementwise_fma(hr[k], niw, hb);
        h[k] = hln * rs[k];
      }

      // readout partial: sd = sum_j h_j * c_j over this lane's 8 states
      v2f d = h[0] * cc[0];
      d = __builtin_elementwise_fma(h[1], cc[1], d);
      d = __builtin_elementwise_fma(h[2], cc[2], d);
      d = __builtin_elementwise_fma(h[3], cc[3], d);
      float sd = d.x + d.y;
      if constexpr (PART) sacc[u] = sd;
      else                sacc[u] = wave_sum64(sd);
    }
    if constexpr (PART) {
#pragma unroll
      for (int u = 0; u < BLK; ++u) pp[(size_t)(T + u) * 64 + lane] = sacc[u];
    } else {
      if (lane == 63) {
#pragma unroll
        for (int u = 0; u < BLK; ++u) pp[T + u] = sacc[u];
      }
    }
  };

  // software pipeline, pinned with sched_barrier so prefetch loads cannot sink
  load_blk(XA, RA, VA, 0);
  __builtin_amdgcn_sched_barrier(0);
  int T = 0;
#pragma unroll 1
  for (int it = 0; it < NB / 2 - 1; ++it, T += 2 * BLK) {
    load_blk(XB, RB, VB, T + BLK);
    __builtin_amdgcn_sched_barrier(0);
    proc_blk(XA, RA, VA, T);
    __builtin_amdgcn_sched_barrier(0);
    load_blk(XA, RA, VA, T + 2 * BLK);
    __builtin_amdgcn_sched_barrier(0);
    proc_blk(XB, RB, VB, T + BLK);
    __builtin_amdgcn_sched_barrier(0);
  }
  load_blk(XB, RB, VB, T + BLK);
  proc_blk(XA, RA, VA, T);
  proc_blk(XB, RB, VB, T + BLK);
}

// ------- epilogue A: reduce 64 partials per (b,t), then out = coef*x + c1*s -------
__global__ __launch_bounds__(256) void out_part(
    const float* __restrict__ x, const float* __restrict__ part,
    const float* __restrict__ alpha_p, const float* __restrict__ logd_p,
    float* __restrict__ out)
{
  const int lane = threadIdx.x & 63;
  const size_t bt = (size_t)blockIdx.x * 4 + (threadIdx.x >> 6);  // wave per (b,t) row

  float al   = 1.0f / (1.0f + expf(-alpha_p[0]));
  float dd   = expf(logd_p[0]);
  float coef = __builtin_fmaf(1.0f - al, dd, al);
  float c1   = 1.0f - al;

  float p = part[bt * 64 + lane];
  float s = bcast63(wave_sum64(p)) * c1;

  const v4f* x4 = (const v4f*)x;
  v4f* o4 = (v4f*)out;
  size_t base = bt * 128;
#pragma unroll
  for (int j = 0; j < 2; ++j) {
    size_t i = base + lane + (size_t)j * 64;
    v4f xv = x4[i];
    o4[i] = xv * coef + s;
  }
}

// ------- epilogue B: s already reduced to one scalar per (b,t) -------
__global__ __launch_bounds__(256) void out_scalar(
    const float* __restrict__ x, const float* __restrict__ sp,
    const float* __restrict__ alpha_p, const float* __restrict__ logd_p,
    float* __restrict__ out)
{
  const int lane = threadIdx.x & 63;
  const size_t bt = (size_t)blockIdx.x * 4 + (threadIdx.x >> 6);

  float al   = 1.0f / (1.0f + expf(-alpha_p[0]));
  float dd   = expf(logd_p[0]);
  float coef = __builtin_fmaf(1.0f - al, dd, al);
  float c1   = 1.0f - al;

  float s = sp[bt] * c1;
  const v4f* x4 = (const v4f*)x;
  v4f* o4 = (v4f*)out;
  size_t base = bt * 128;
#pragma unroll
  for (int j = 0; j < 2; ++j) {
    size_t i = base + lane + (size_t)j * 64;
    v4f xv = x4[i];
    o4[i] = xv * coef + s;
  }
}

extern "C" void kernel_launch(void* const* d_in, const int* in_sizes, int n_in,
                              void* d_out, int out_size, void* d_ws, size_t ws_size,
                              hipStream_t stream) {
  const float* x    = (const float*)d_in[0];   // [8,4096,512]
  const float* vol  = (const float*)d_in[1];   // [8,4096,1]
  const float* llr  = (const float*)d_in[2];   // [512]
  const float* logb = (const float*)d_in[3];   // [512,1]
  const float* cvec = (const float*)d_in[4];   // [1,512]
  const float* logd = (const float*)d_in[5];   // [1]
  const float* lstp = (const float*)d_in[6];   // [512]
  const float* vgat = (const float*)d_in[7];   // [512]
  const float* alph = (const float*)d_in[8];   // [1]
  const float* lnw  = (const float*)d_in[9];   // [512]
  const float* lnb  = (const float*)d_in[10];  // [512]
  float* wsf = (float*)d_ws;
  float* outf = (float*)d_out;

  const size_t rg_elems   = (size_t)BATCH * SEQ * DS;   // 16M floats = 64 MB
  const size_t part_elems = (size_t)BATCH * SEQ * 64;   // 2M floats  = 8 MB

  if (ws_size >= (rg_elems + part_elems) * sizeof(float)) {
    float* rg   = wsf;
    float* part = wsf + rg_elems;
    rg_kernel<<<(BATCH * SEQ * 128) / 256, 256, 0, stream>>>(vol, vgat, rg);
    ssm_scan<true, true><<<BATCH, 64, 0, stream>>>(x, vol, llr, logb, cvec, lstp,
                                                   vgat, lnw, lnb, rg, part);
    out_part<<<BATCH * SEQ / 4, 256, 0, stream>>>(x, part, alph, logd, outf);
  } else if (ws_size >= part_elems * sizeof(float)) {
    float* part = wsf;
    ssm_scan<false, true><<<BATCH, 64, 0, stream>>>(x, vol, llr, logb, cvec, lstp,
                                                    vgat, lnw, lnb, nullptr, part);
    out_part<<<BATCH * SEQ / 4, 256, 0, stream>>>(x, part, alph, logd, outf);
  } else {
    float* sp = wsf;  // BATCH*SEQ floats = 128 KB
    ssm_scan<false, false><<<BATCH, 64, 0, stream>>>(x, vol, llr, logb, cvec, lstp,
                                                     vgat, lnw, lnb, nullptr, sp);
    out_scalar<<<BATCH * SEQ / 4, 256, 0, stream>>>(x, sp, alph, logd, outf);
  }
}

// Round 4
// 697.199 us; speedup vs baseline: 1.5396x; 1.1088x over previous
//
#include <hip/hip_runtime.h>
#include <cstdint>
#include <cstddef>

#define BATCH 8
#define SEQ   4096
#define DS    512
#define JPL   8              // states per lane (64 lanes * 8 = 512)
#define BLK   8              // time steps per LDS block
#define NBLK  (SEQ / BLK)    // 512 (even)

typedef float v2f __attribute__((ext_vector_type(2)));
typedef float v4f __attribute__((ext_vector_type(4)));

static __device__ __forceinline__ v2f lo2(v4f x) { return __builtin_shufflevector(x, x, 0, 1); }
static __device__ __forceinline__ v2f hi2(v4f x) { return __builtin_shufflevector(x, x, 2, 3); }

// ---- DPP wave64 reduction: row_shr 1/2/4/8, row_bcast15/31 -> lane 63 ----
template <int CTRL>
__device__ __forceinline__ float dpp_add(float v) {
  int t = __builtin_amdgcn_update_dpp(0, __builtin_bit_cast(int, v), CTRL, 0xF, 0xF, true);
  return v + __builtin_bit_cast(float, t);
}
__device__ __forceinline__ float wave_sum64(float v) {
  v = dpp_add<0x111>(v);
  v = dpp_add<0x112>(v);
  v = dpp_add<0x114>(v);
  v = dpp_add<0x118>(v);
  v = dpp_add<0x142>(v);
  v = dpp_add<0x143>(v);
  return v;  // valid in lane 63
}
__device__ __forceinline__ float bcast63(float v) {
  return __builtin_bit_cast(float, __builtin_amdgcn_readlane(__builtin_bit_cast(int, v), 63));
}

// async HBM -> LDS: per-lane 16B from g, LDS dest = uniform base + lane*16
__device__ __forceinline__ void ld16(const float* g, float* l) {
  __builtin_amdgcn_global_load_lds(
      (const __attribute__((address_space(1))) void*)g,
      (__attribute__((address_space(3))) void*)l, 16, 0, 0);
}

// ---------------- scan kernel: 3 waves per batch element --------------------
// wave 0: consumer (recurrence; LDS-only, fully fenced barriers)
// wave 1: DMA x into LDS + reduce/store previous block's readout scalars
// wave 2: rg = 1/(1+sigmoid(g)*v) into LDS (vol prefetched one interval ahead)
__global__ __launch_bounds__(192, 1) void ssm_scan(
    const float* __restrict__ x, const float* __restrict__ vol,
    const float* __restrict__ llr, const float* __restrict__ logb,
    const float* __restrict__ cvec, const float* __restrict__ lstp,
    const float* __restrict__ vgat, const float* __restrict__ lnw,
    const float* __restrict__ lnb, float* __restrict__ sp)
{
  __shared__ float X0[4096], X1[4096];   // x tiles (8 steps x 512)
  __shared__ float R0[4096], R1[4096];   // rg tiles
  __shared__ float SC0[512], SC1[512];   // per-lane readout partials (8 x 64)

  const int b    = blockIdx.x;
  const int lane = threadIdx.x & 63;
  const int wid  = threadIdx.x >> 6;

  if (wid == 1) {
    // ===================== DMA + reduce/copy wave =====================
    const float* xg = x + (size_t)b * SEQ * DS + lane * JPL;
    float* spb = sp + (size_t)b * SEQ;

    auto dma_blk = [&](int blk, float* Xs) {
#pragma unroll
      for (int u = 0; u < BLK; ++u) {
        const float* row = xg + (size_t)(blk * BLK + u) * DS;
        ld16(row,     Xs + u * 512);         // floats [8l..8l+3] -> [4l..4l+3]
        ld16(row + 4, Xs + u * 512 + 256);   // floats [8l+4..8l+7]
      }
    };
    auto red_copy = [&](const float* SCs, int blk) {
      float s[BLK];
#pragma unroll
      for (int u = 0; u < BLK; ++u) s[u] = wave_sum64(SCs[u * 64 + lane]);
      if (lane == 63) {
#pragma unroll
        for (int u = 0; u < BLK; ++u) spb[blk * BLK + u] = s[u];
      }
    };

    dma_blk(0, X0);
    __syncthreads();  // B0: block 0 staged
#pragma unroll 1
    for (int i2 = 0; i2 < NBLK; i2 += 2) {
      dma_blk(i2 + 1, X1);                       // stage block i2+1
      if (i2 > 0) red_copy(SC1, i2 - 1);         // block i2-1 scalars (sealed)
      __syncthreads();
      if (i2 + 2 < NBLK) dma_blk(i2 + 2, X0);    // stage block i2+2
      red_copy(SC0, i2);                         // block i2 scalars (sealed)
      __syncthreads();
    }
    red_copy(SC1, NBLK - 1);                     // final block's scalars
  } else if (wid == 2) {
    // ===================== gate-reciprocal wave =====================
    v2f gate[4];
#pragma unroll
    for (int j = 0; j < JPL; ++j)
      gate[j >> 1][j & 1] = 1.0f / (1.0f + expf(-vgat[lane * JPL + j]));
    const float* vg = vol + (size_t)b * SEQ;

    auto rg_blk = [&](v4f Va, v4f Vb, float* Rs) {
#pragma unroll
      for (int u = 0; u < BLK; ++u) {
        float vt = (u < 4) ? Va[u] : Vb[u - 4];
        v4f r0, r1;
#pragma unroll
        for (int k = 0; k < 4; ++k) {
          v2f den = gate[k] * vt + 1.0f;
          float q0 = __builtin_amdgcn_rcpf(den.x);
          float q1 = __builtin_amdgcn_rcpf(den.y);
          if (k < 2) { r0[2 * k] = q0; r0[2 * k + 1] = q1; }
          else       { r1[2 * (k - 2)] = q0; r1[2 * (k - 2) + 1] = q1; }
        }
        *(v4f*)(Rs + u * 512 + lane * 4)       = r0;
        *(v4f*)(Rs + u * 512 + 256 + lane * 4) = r1;
      }
    };

    v4f V0a = *(const v4f*)(vg + 0), V0b = *(const v4f*)(vg + 4);
    v4f V1a = *(const v4f*)(vg + 8), V1b = *(const v4f*)(vg + 12);
    rg_blk(V0a, V0b, R0);                        // block 0
    __syncthreads();  // B0
#pragma unroll 1
    for (int i2 = 0; i2 < NBLK; i2 += 2) {
      if (i2 + 2 < NBLK) {                       // prefetch vol for block i2+2
        V0a = *(const v4f*)(vg + (i2 + 2) * BLK);
        V0b = *(const v4f*)(vg + (i2 + 2) * BLK + 4);
      }
      rg_blk(V1a, V1b, R1);                      // block i2+1
      __syncthreads();
      if (i2 + 3 < NBLK) {                       // prefetch vol for block i2+3
        V1a = *(const v4f*)(vg + (i2 + 3) * BLK);
        V1b = *(const v4f*)(vg + (i2 + 3) * BLK + 4);
      }
      if (i2 + 2 < NBLK) rg_blk(V0a, V0b, R0);   // block i2+2
      __syncthreads();
    }
  } else {
    // ========================= consumer wave =========================
    v2f a[4], bd[4], w[4], bias[4], cc[4];
#pragma unroll
    for (int j = 0; j < JPL; ++j) {
      int n = lane * JPL + j;
      float lam = -expf(llr[n]);
      float st  = expf(lstp[n]);
      float z   = st * lam;
      float ad  = (2.0f + z) / (2.0f - z);
      a[j >> 1][j & 1]    = ad;
      bd[j >> 1][j & 1]   = st * (1.0f + ad) * expf(logb[n]) * 0.5f;
      w[j >> 1][j & 1]    = lnw[n];
      bias[j >> 1][j & 1] = lnb[n];
      cc[j >> 1][j & 1]   = cvec[n];
    }
    v2f h[4];
#pragma unroll
    for (int k = 0; k < 4; ++k) h[k] = (v2f){0.0f, 0.0f};

    auto proc_blk = [&](const float* Xs, const float* Rs, float* SCs) {
#pragma unroll
      for (int u = 0; u < BLK; ++u) {
        v4f xx0 = *(const v4f*)(Xs + u * 512 + lane * 4);
        v4f xx1 = *(const v4f*)(Xs + u * 512 + 256 + lane * 4);
        v4f rr0 = *(const v4f*)(Rs + u * 512 + lane * 4);
        v4f rr1 = *(const v4f*)(Rs + u * 512 + 256 + lane * 4);
        v2f xs[4] = {lo2(xx0), hi2(xx0), lo2(xx1), hi2(xx1)};
        v2f rs[4] = {lo2(rr0), hi2(rr0), lo2(rr1), hi2(rr1)};

        v2f hr[4];
#pragma unroll
        for (int k = 0; k < 4; ++k)
          hr[k] = __builtin_elementwise_fma(a[k], h[k], bd[k] * xs[k]);

        v2f ts = (hr[0] + hr[1]) + (hr[2] + hr[3]);
        float s1 = ts.x + ts.y;
        v2f qs = (hr[0] * hr[0] + hr[1] * hr[1]) + (hr[2] * hr[2] + hr[3] * hr[3]);
        float s2 = qs.x + qs.y;

        s1 = bcast63(wave_sum64(s1));
        s2 = bcast63(wave_sum64(s2));
        float mu  = s1 * (1.0f / DS);
        float m2  = s2 * (1.0f / DS);
        float var = __builtin_fmaf(-mu, mu, m2);
        float inv = __builtin_amdgcn_rsqf(var + 1e-5f);

#pragma unroll
        for (int k = 0; k < 4; ++k) {
          v2f niw = w[k] * inv;
          v2f hb  = bias[k] - niw * mu;
          v2f hln = __builtin_elementwise_fma(hr[k], niw, hb);
          h[k] = hln * rs[k];
        }

        v2f d = h[0] * cc[0];
        d = __builtin_elementwise_fma(h[1], cc[1], d);
        d = __builtin_elementwise_fma(h[2], cc[2], d);
        d = __builtin_elementwise_fma(h[3], cc[3], d);
        SCs[u * 64 + lane] = d.x + d.y;   // per-lane readout partial
      }
    };

    __syncthreads();  // B0
#pragma unroll 1
    for (int i2 = 0; i2 < NBLK; i2 += 2) {
      proc_blk(X0, R0, SC0);
      __syncthreads();
      proc_blk(X1, R1, SC1);
      __syncthreads();
    }
  }
}

// ------- epilogue: out = coef*x + c1*s[b,t] (s already reduced) -------
__global__ __launch_bounds__(256) void out_scalar(
    const float* __restrict__ x, const float* __restrict__ sp,
    const float* __restrict__ alpha_p, const float* __restrict__ logd_p,
    float* __restrict__ out)
{
  const int lane = threadIdx.x & 63;
  const size_t bt = (size_t)blockIdx.x * 4 + (threadIdx.x >> 6);

  float al   = 1.0f / (1.0f + expf(-alpha_p[0]));
  float dd   = expf(logd_p[0]);
  float coef = __builtin_fmaf(1.0f - al, dd, al);
  float c1   = 1.0f - al;

  float s = sp[bt] * c1;
  const v4f* x4 = (const v4f*)x;
  v4f* o4 = (v4f*)out;
  size_t base = bt * 128;
#pragma unroll
  for (int j = 0; j < 2; ++j) {
    size_t i = base + lane + (size_t)j * 64;
    v4f xv = x4[i];
    o4[i] = xv * coef + s;
  }
}

extern "C" void kernel_launch(void* const* d_in, const int* in_sizes, int n_in,
                              void* d_out, int out_size, void* d_ws, size_t ws_size,
                              hipStream_t stream) {
  const float* x    = (const float*)d_in[0];   // [8,4096,512]
  const float* vol  = (const float*)d_in[1];   // [8,4096,1]
  const float* llr  = (const float*)d_in[2];   // [512]
  const float* logb = (const float*)d_in[3];   // [512,1]
  const float* cvec = (const float*)d_in[4];   // [1,512]
  const float* logd = (const float*)d_in[5];   // [1]
  const float* lstp = (const float*)d_in[6];   // [512]
  const float* vgat = (const float*)d_in[7];   // [512]
  const float* alph = (const float*)d_in[8];   // [1]
  const float* lnw  = (const float*)d_in[9];   // [512]
  const float* lnb  = (const float*)d_in[10];  // [512]
  float* sp   = (float*)d_ws;                  // BATCH*SEQ floats = 128 KB
  float* outf = (float*)d_out;

  ssm_scan<<<BATCH, 192, 0, stream>>>(x, vol, llr, logb, cvec, lstp,
                                      vgat, lnw, lnb, sp);
  out_scalar<<<BATCH * SEQ / 4, 256, 0, stream>>>(x, sp, alph, logd, outf);
}